// Round 20
// baseline (32.642 us; speedup 1.0000x reference)
//
#include <hip/hip_runtime.h>
#include <hip/hip_bf16.h>

#define LL 50
#define DD 64
#define NCATS 1000
#define NRAT 5

// ws byte offsets
#define OFF_H    0          // ushort[1000*5*64] = 640000 B (bf16 H table)
#define OFF_M1T  640000     // ushort[64*64] bf16 (M1t[d][e] = (Wq Wk^T)[e][d])
#define OFF_WVOT 648192     // ushort[64*64] bf16 (Wvot[d][e] = (Wv Wo)[e][d])
#define OFF_BKQ  656384     // float[64]  (Wk @ bq)
#define OFF_BVO  656640     // float[64]  (bv @ Wo + bo)

typedef __attribute__((ext_vector_type(8))) short short8;
typedef __attribute__((ext_vector_type(4))) float f32x4;

union U4S8 { uint4 u4; short8 s8; };

__device__ __forceinline__ float rlanef(float v, int l) {
  return __uint_as_float(__builtin_amdgcn_readlane(__float_as_uint(v), l));
}
// HW packed f32->bf16 (RNE)
__device__ __forceinline__ unsigned int pk2bf(float lo, float hi) {
  unsigned int r;
  asm("v_cvt_pk_bf16_f32 %0, %1, %2" : "=v"(r) : "v"(lo), "v"(hi));
  return r;
}
__device__ __forceinline__ unsigned short f2bf(float f) {
  unsigned int r;
  asm("v_cvt_pk_bf16_f32 %0, %1, %1" : "=v"(r) : "v"(f));
  return (unsigned short)r;
}
__device__ __forceinline__ short8 pack8(float4 f0, float4 f1) {
  U4S8 t;
  t.u4.x = pk2bf(f0.x, f0.y); t.u4.y = pk2bf(f0.z, f0.w);
  t.u4.z = pk2bf(f1.x, f1.y); t.u4.w = pk2bf(f1.z, f1.w);
  return t.s8;
}

// ---------------- prep_v3: BYTE-IDENTICAL to rounds 17-19 (passed) ----------------
__global__ __launch_bounds__(256) void prep_v3(
    const float* __restrict__ c2e, const float* __restrict__ r2e,
    const float* __restrict__ W1, const float* __restrict__ b1,
    const float* __restrict__ Wq, const float* __restrict__ bq,
    const float* __restrict__ Wk, const float* __restrict__ Wv,
    const float* __restrict__ Wo, const float* __restrict__ bv,
    const float* __restrict__ bo, char* __restrict__ ws) {
  unsigned short* H = (unsigned short*)(ws + OFF_H);
  unsigned short* M1T = (unsigned short*)(ws + OFF_M1T);
  unsigned short* WVOT = (unsigned short*)(ws + OFF_WVOT);
  float* BKQ = (float*)(ws + OFF_BKQ);
  float* BVO = (float*)(ws + OFF_BVO);

  const int tid = threadIdx.x;
  const int wid = tid >> 6;
  const int lane = tid & 63;
  const int kg = lane >> 4;
  const int rw = lane & 15;
  const int b = blockIdx.x;

  if (b < 250) {
    const int vc = __builtin_amdgcn_readfirstlane(b * 4 + wid);  // 250*4 = 1000
    const float* __restrict__ crow = c2e + (size_t)vc * DD;
    float ac = 0.f, q0 = 0.f, q1 = 0.f, q2 = 0.f, q3 = 0.f, q4 = 0.f;
#pragma unroll 8
    for (int e = 0; e < DD; ++e) {
      const float wa = W1[(size_t)e * DD + lane];
      const float wb = W1[(size_t)(DD + e) * DD + lane];
      ac = fmaf(crow[e], wa, ac);
      q0 = fmaf(r2e[0 * DD + e], wb, q0);
      q1 = fmaf(r2e[1 * DD + e], wb, q1);
      q2 = fmaf(r2e[2 * DD + e], wb, q2);
      q3 = fmaf(r2e[3 * DD + e], wb, q3);
      q4 = fmaf(r2e[4 * DD + e], wb, q4);
    }
    const float base = ac + b1[lane];
    unsigned short* __restrict__ hrow = H + (size_t)vc * NRAT * DD + lane;
    hrow[0 * DD] = f2bf(fmaxf(base + q0, 0.f));
    hrow[1 * DD] = f2bf(fmaxf(base + q1, 0.f));
    hrow[2 * DD] = f2bf(fmaxf(base + q2, 0.f));
    hrow[3 * DD] = f2bf(fmaxf(base + q3, 0.f));
    hrow[4 * DD] = f2bf(fmaxf(base + q4, 0.f));
  } else if (b == 250) {
    short8 aq[2];
#pragma unroll
    for (int ks = 0; ks < 2; ++ks) {
      const float* __restrict__ p = Wq + (size_t)(wid * 16 + rw) * DD + ks * 32 + kg * 8;
      aq[ks] = pack8(*(const float4*)(p), *(const float4*)(p + 4));
    }
#pragma unroll
    for (int n0 = 0; n0 < 4; ++n0) {
      f32x4 a = {0.f, 0.f, 0.f, 0.f};
#pragma unroll
      for (int ks = 0; ks < 2; ++ks) {
        const float* __restrict__ p = Wk + (size_t)(n0 * 16 + rw) * DD + ks * 32 + kg * 8;
        const short8 bf = pack8(*(const float4*)(p), *(const float4*)(p + 4));
        a = __builtin_amdgcn_mfma_f32_16x16x32_bf16(aq[ks], bf, a, 0, 0, 0);
      }
#pragma unroll
      for (int r = 0; r < 4; ++r) {
        M1T[(size_t)(n0 * 16 + rw) * DD + wid * 16 + kg * 4 + r] = f2bf(a[r]);
      }
    }
    if (wid == 0) {
      const float* __restrict__ wrow = Wk + (size_t)lane * DD;
      float a0 = 0.f, a1 = 0.f, a2 = 0.f, a3 = 0.f;
#pragma unroll
      for (int t2 = 0; t2 < DD; t2 += 4) {
        const float4 w4 = *(const float4*)(wrow + t2);
        a0 = fmaf(w4.x, bq[t2 + 0], a0);
        a1 = fmaf(w4.y, bq[t2 + 1], a1);
        a2 = fmaf(w4.z, bq[t2 + 2], a2);
        a3 = fmaf(w4.w, bq[t2 + 3], a3);
      }
      BKQ[lane] = (a0 + a1) + (a2 + a3);
    }
  } else {
    short8 ao[2];
#pragma unroll
    for (int ks = 0; ks < 2; ++ks) {
      U4S8 t4;
#pragma unroll
      for (int j = 0; j < 4; ++j) {
        const int k = ks * 32 + kg * 8 + 2 * j;
        const int col = wid * 16 + rw;
        ((unsigned int*)&t4)[j] = pk2bf(Wo[(size_t)k * DD + col],
                                        Wo[(size_t)(k + 1) * DD + col]);
      }
      ao[ks] = t4.s8;
    }
#pragma unroll
    for (int n0 = 0; n0 < 4; ++n0) {
      f32x4 a = {0.f, 0.f, 0.f, 0.f};
#pragma unroll
      for (int ks = 0; ks < 2; ++ks) {
        const float* __restrict__ p = Wv + (size_t)(n0 * 16 + rw) * DD + ks * 32 + kg * 8;
        const short8 bf = pack8(*(const float4*)(p), *(const float4*)(p + 4));
        a = __builtin_amdgcn_mfma_f32_16x16x32_bf16(ao[ks], bf, a, 0, 0, 0);
      }
#pragma unroll
      for (int r = 0; r < 4; ++r) {
        WVOT[(size_t)(wid * 16 + kg * 4 + r) * DD + n0 * 16 + rw] = f2bf(a[r]);
      }
    }
    if (wid == 0) {
      float acc = bo[lane];
#pragma unroll 8
      for (int t2 = 0; t2 < DD; ++t2) acc = fmaf(bv[t2], Wo[(size_t)t2 * DD + lane], acc);
      BVO[lane] = acc;
    }
  }
}

// ---------------- main v3.2: r19 structure + T5 setprio around MFMA clusters ----------------
// ONLY change vs r19: __builtin_amdgcn_s_setprio(1)/(0) wrapping the G, scores,
// and OUT MFMA clusters (phase-diverse waves -> scheduler arbitration pays).
__global__ __launch_bounds__(256, 3) void vc_main(
    const int* __restrict__ nodes, const int* __restrict__ hvc,
    const int* __restrict__ hr, const float* __restrict__ v2e,
    const char* __restrict__ ws, float* __restrict__ out, int N) {
  const unsigned short* __restrict__ H = (const unsigned short*)(ws + OFF_H);
  const unsigned short* __restrict__ M1T = (const unsigned short*)(ws + OFF_M1T);
  const unsigned short* __restrict__ WVOT = (const unsigned short*)(ws + OFF_WVOT);
  const float* __restrict__ BKQ = (const float*)(ws + OFF_BKQ);
  const float* __restrict__ BVO = (const float*)(ws + OFF_BVO);

  __shared__ __align__(16) char smem[8 * 6400 + 8 * 68 * 4];
  char* HlB = smem;
  float* sS = (float*)(smem + 8 * 6400);

  const int tid = threadIdx.x;
  const int wid = tid >> 6;    // 0..3; d-quarter n0 == wid
  const int lane = tid & 63;
  const int kg = lane >> 4;
  const int rw = lane & 15;
  const int nb = blockIdx.x * 8;
  const int nA = min(nb + wid, N - 1);
  const int nB = min(nb + 4 + wid, N - 1);

  const int lidx = (lane < LL) ? lane : 0;
  const int idxA = hvc[(size_t)nA * LL + lidx] * NRAT + hr[(size_t)nA * LL + lidx];
  const int idxB = hvc[(size_t)nB * LL + lidx] * NRAT + hr[(size_t)nB * LL + lidx];

  // ---- stage BOTH nodes' H tiles (14 x global_load_lds) ----
  {
    const int chunk = lane & 7;
#pragma unroll
    for (int ph = 0; ph < 2; ++ph) {
      const int idx = ph ? idxB : idxA;
      char* wbase = HlB + (ph ? (4 + wid) : wid) * 6400;
#pragma unroll
      for (int i = 0; i < 7; ++i) {
        const int s = (i < 6) ? (i * 8 + (lane >> 3)) : (42 + (lane >> 3));
        const int sidx = __shfl(idx, s, 64);
        const char* src = (const char*)H + (size_t)sidx * 128 + ((chunk ^ (s & 7)) << 4);
        __builtin_amdgcn_global_load_lds(
            (const __attribute__((address_space(1))) void*)src,
            (__attribute__((address_space(3))) void*)(wbase + ((i < 6) ? i * 1024 : 5376)),
            16, 0, 0);
      }
    }
  }

  // ---- G = X @ M1 + bkq for ALL 8 nodes ----
  {
    const int node_id = nodes[min(nb + (rw & 7), N - 1)];
    const float* __restrict__ xrow = v2e + (size_t)node_id * DD;
    short8 xa[2];
#pragma unroll
    for (int ks = 0; ks < 2; ++ks) {
      xa[ks] = pack8(*(const float4*)(xrow + ks * 32 + kg * 8),
                     *(const float4*)(xrow + ks * 32 + kg * 8 + 4));
    }
    const int n0 = wid;
    f32x4 a = {0.f, 0.f, 0.f, 0.f};
    __builtin_amdgcn_s_setprio(1);
#pragma unroll
    for (int ks = 0; ks < 2; ++ks) {
      const short8 bf = *(const short8*)(M1T + (n0 * 16 + rw) * DD + ks * 32 + kg * 8);
      a = __builtin_amdgcn_mfma_f32_16x16x32_bf16(xa[ks], bf, a, 0, 0, 0);
    }
    __builtin_amdgcn_s_setprio(0);
    if (kg < 2) {   // C rows 0..7 = nodes 0..7
      const float bkqv = BKQ[n0 * 16 + rw];
#pragma unroll
      for (int r = 0; r < 4; ++r) sS[(kg * 4 + r) * 68 + n0 * 16 + rw] = a[r] + bkqv;
    }
  }
  __syncthreads();
  asm volatile("s_waitcnt vmcnt(7)" ::: "memory");  // node A staged; B in flight
  __builtin_amdgcn_sched_barrier(0);

  // ---- ctx base offsets: addr(l) = (l>>3)*1024 + baseo[l&7] (precomputed) ----
  const int sub = (lane & 7) * 2;
  const int hi3 = lane >> 3;
  int baseo[8];
#pragma unroll
  for (int j = 0; j < 8; ++j) baseo[j] = j * 128 + (((hi3 ^ j) << 4) | sub);

  // ---- two per-node phases: A (row wid), then B (row 4+wid) ----
#pragma unroll
  for (int ph = 0; ph < 2; ++ph) {
    const int myrow = ph ? (4 + wid) : wid;
    if (ph == 1) {
      asm volatile("s_waitcnt vmcnt(0)" ::: "memory");  // node B staged
      __builtin_amdgcn_sched_barrier(0);
    }
    const unsigned short* __restrict__ wH =
        (const unsigned short*)(HlB + myrow * 6400);

    short8 ga[2];
#pragma unroll
    for (int ks = 0; ks < 2; ++ks) {
      const float* __restrict__ gp = sS + myrow * 68 + ks * 32 + kg * 8;
      ga[ks] = pack8(*(const float4*)(gp), *(const float4*)(gp + 4));
    }
    float s0, s1, s2, s3;
    {
      f32x4 a;
      __builtin_amdgcn_s_setprio(1);
#pragma unroll
      for (int lt = 0; lt < 4; ++lt) {
        const int s = lt * 16 + rw;
        a = (f32x4){0.f, 0.f, 0.f, 0.f};
#pragma unroll
        for (int ks = 0; ks < 2; ++ks) {
          const int c = (ks * 4 + kg) ^ (s & 7);
          U4S8 hb;
          hb.u4 = *(const uint4*)(wH + s * 64 + c * 8);
          a = __builtin_amdgcn_mfma_f32_16x16x32_bf16(ga[ks], hb.s8, a, 0, 0, 0);
        }
        if (lt == 0) s0 = a[0];
        else if (lt == 1) s1 = a[0];
        else if (lt == 2) s2 = a[0];
        else s3 = a[0];
      }
      __builtin_amdgcn_s_setprio(0);
    }
    s0 *= 0.125f; s1 *= 0.125f; s2 *= 0.125f;
    s3 = (rw < 2) ? s3 * 0.125f : -INFINITY;

    float m = fmaxf(fmaxf(s0, s1), fmaxf(s2, s3));
#pragma unroll
    for (int x = 1; x <= 8; x <<= 1) m = fmaxf(m, __shfl_xor(m, x, 64));
    float e0 = __expf(s0 - m), e1 = __expf(s1 - m), e2 = __expf(s2 - m);
    float e3 = (rw < 2) ? __expf(s3 - m) : 0.f;
    float Z = ((e0 + e1) + (e2 + e3));
#pragma unroll
    for (int x = 1; x <= 8; x <<= 1) Z += __shfl_xor(Z, x, 64);
    const float invZ = 1.f / Z;

    {
      const char* __restrict__ wHb = (const char*)wH;
      float c0 = 0.f, c1 = 0.f;
#define CTX_BLOCK(EREG, BASE, CNT, CACC)                                        \
      _Pragma("unroll")                                                         \
      for (int j = 0; j < (CNT); ++j) {                                         \
        const int l = (BASE) + j;                                               \
        const unsigned short hbb = *(const unsigned short*)(                    \
            wHb + baseo[l & 7] + (l >> 3) * 1024);                              \
        CACC = fmaf(__uint_as_float(((unsigned int)hbb) << 16),                 \
                    rlanef(EREG, j), CACC);                                     \
      }
      CTX_BLOCK(e0, 0, 16, c0)
      CTX_BLOCK(e1, 16, 16, c1)
      CTX_BLOCK(e2, 32, 16, c0)
      CTX_BLOCK(e3, 48, 2, c1)
#undef CTX_BLOCK
      sS[myrow * 68 + lane] = (c0 + c1) * invZ;   // overwrite own row
    }
  }
  __syncthreads();

  // ---- OUT = CTX @ Wvo + bvo for all 8 nodes ----
  {
    short8 ca[2];
#pragma unroll
    for (int ks = 0; ks < 2; ++ks) {
      const float* __restrict__ cp = sS + (rw & 7) * 68 + ks * 32 + kg * 8;
      ca[ks] = pack8(*(const float4*)(cp), *(const float4*)(cp + 4));
    }
    const int n0 = wid;
    f32x4 a = {0.f, 0.f, 0.f, 0.f};
    __builtin_amdgcn_s_setprio(1);
#pragma unroll
    for (int ks = 0; ks < 2; ++ks) {
      const short8 bf = *(const short8*)(WVOT + (n0 * 16 + rw) * DD + ks * 32 + kg * 8);
      a = __builtin_amdgcn_mfma_f32_16x16x32_bf16(ca[ks], bf, a, 0, 0, 0);
    }
    __builtin_amdgcn_s_setprio(0);
    if (kg < 2) {   // C rows 0..7 = nodes 0..7
      const float bvov = BVO[n0 * 16 + rw];
#pragma unroll
      for (int r = 0; r < 4; ++r) {
        const int node = nb + kg * 4 + r;
        if (node < N) out[(size_t)node * DD + n0 * 16 + rw] = a[r] + bvov;
      }
    }
  }
}

extern "C" void kernel_launch(void* const* d_in, const int* in_sizes, int n_in,
                              void* d_out, int out_size, void* d_ws, size_t ws_size,
                              hipStream_t stream) {
  const int* nodes = (const int*)d_in[0];
  const int* hvc = (const int*)d_in[1];
  const int* hr = (const int*)d_in[2];
  const float* c2e = (const float*)d_in[3];
  const float* v2e = (const float*)d_in[4];
  const float* r2e = (const float*)d_in[5];
  const float* W1 = (const float*)d_in[6];
  const float* b1 = (const float*)d_in[7];
  const float* Wq = (const float*)d_in[8];
  const float* bq = (const float*)d_in[9];
  const float* Wk = (const float*)d_in[10];
  const float* bk = (const float*)d_in[11];  // unused: q·bk cancels in softmax
  const float* Wv = (const float*)d_in[12];
  const float* bv = (const float*)d_in[13];
  const float* Wo = (const float*)d_in[14];
  const float* bo = (const float*)d_in[15];
  (void)bk;
  float* out = (float*)d_out;
  char* ws = (char*)d_ws;

  const int N = in_sizes[0];

  prep_v3<<<252, 256, 0, stream>>>(c2e, r2e, W1, b1, Wq, bq, Wk, Wv, Wo, bv, bo, ws);
  vc_main<<<(N + 7) / 8, 256, 0, stream>>>(nodes, hvc, hr, v2e, ws, out, N);
}

// Round 22
// 32.158 us; speedup vs baseline: 1.0150x; 1.0150x over previous
//
#include <hip/hip_runtime.h>
#include <hip/hip_bf16.h>

#define LL 50
#define DD 64
#define NCATS 1000
#define NRAT 5

// ws byte offsets
#define OFF_H    0          // ushort[1000*5*64] = 640000 B (bf16 H table)
#define OFF_M1T  640000     // ushort[64*64] bf16 (M1t[d][e] = (Wq Wk^T)[e][d])
#define OFF_WVOT 648192     // ushort[64*64] bf16 (Wvot[d][e] = (Wv Wo)[e][d])
#define OFF_BKQ  656384     // float[64]  (Wk @ bq)
#define OFF_BVO  656640     // float[64]  (bv @ Wo + bo)

typedef __attribute__((ext_vector_type(8))) short short8;
typedef __attribute__((ext_vector_type(4))) float f32x4;

union U4S8 { uint4 u4; short8 s8; };

__device__ __forceinline__ float rlanef(float v, int l) {
  return __uint_as_float(__builtin_amdgcn_readlane(__float_as_uint(v), l));
}
// HW packed f32->bf16 (RNE)
__device__ __forceinline__ unsigned int pk2bf(float lo, float hi) {
  unsigned int r;
  asm("v_cvt_pk_bf16_f32 %0, %1, %2" : "=v"(r) : "v"(lo), "v"(hi));
  return r;
}
__device__ __forceinline__ unsigned short f2bf(float f) {
  unsigned int r;
  asm("v_cvt_pk_bf16_f32 %0, %1, %1" : "=v"(r) : "v"(f));
  return (unsigned short)r;
}
__device__ __forceinline__ short8 pack8(float4 f0, float4 f1) {
  U4S8 t;
  t.u4.x = pk2bf(f0.x, f0.y); t.u4.y = pk2bf(f0.z, f0.w);
  t.u4.z = pk2bf(f1.x, f1.y); t.u4.w = pk2bf(f1.z, f1.w);
  return t.s8;
}

// ---------------- prep_v3: BYTE-IDENTICAL to rounds 17-19 (passed) ----------------
__global__ __launch_bounds__(256) void prep_v3(
    const float* __restrict__ c2e, const float* __restrict__ r2e,
    const float* __restrict__ W1, const float* __restrict__ b1,
    const float* __restrict__ Wq, const float* __restrict__ bq,
    const float* __restrict__ Wk, const float* __restrict__ Wv,
    const float* __restrict__ Wo, const float* __restrict__ bv,
    const float* __restrict__ bo, char* __restrict__ ws) {
  unsigned short* H = (unsigned short*)(ws + OFF_H);
  unsigned short* M1T = (unsigned short*)(ws + OFF_M1T);
  unsigned short* WVOT = (unsigned short*)(ws + OFF_WVOT);
  float* BKQ = (float*)(ws + OFF_BKQ);
  float* BVO = (float*)(ws + OFF_BVO);

  const int tid = threadIdx.x;
  const int wid = tid >> 6;
  const int lane = tid & 63;
  const int kg = lane >> 4;
  const int rw = lane & 15;
  const int b = blockIdx.x;

  if (b < 250) {
    const int vc = __builtin_amdgcn_readfirstlane(b * 4 + wid);  // 250*4 = 1000
    const float* __restrict__ crow = c2e + (size_t)vc * DD;
    float ac = 0.f, q0 = 0.f, q1 = 0.f, q2 = 0.f, q3 = 0.f, q4 = 0.f;
#pragma unroll 8
    for (int e = 0; e < DD; ++e) {
      const float wa = W1[(size_t)e * DD + lane];
      const float wb = W1[(size_t)(DD + e) * DD + lane];
      ac = fmaf(crow[e], wa, ac);
      q0 = fmaf(r2e[0 * DD + e], wb, q0);
      q1 = fmaf(r2e[1 * DD + e], wb, q1);
      q2 = fmaf(r2e[2 * DD + e], wb, q2);
      q3 = fmaf(r2e[3 * DD + e], wb, q3);
      q4 = fmaf(r2e[4 * DD + e], wb, q4);
    }
    const float base = ac + b1[lane];
    unsigned short* __restrict__ hrow = H + (size_t)vc * NRAT * DD + lane;
    hrow[0 * DD] = f2bf(fmaxf(base + q0, 0.f));
    hrow[1 * DD] = f2bf(fmaxf(base + q1, 0.f));
    hrow[2 * DD] = f2bf(fmaxf(base + q2, 0.f));
    hrow[3 * DD] = f2bf(fmaxf(base + q3, 0.f));
    hrow[4 * DD] = f2bf(fmaxf(base + q4, 0.f));
  } else if (b == 250) {
    short8 aq[2];
#pragma unroll
    for (int ks = 0; ks < 2; ++ks) {
      const float* __restrict__ p = Wq + (size_t)(wid * 16 + rw) * DD + ks * 32 + kg * 8;
      aq[ks] = pack8(*(const float4*)(p), *(const float4*)(p + 4));
    }
#pragma unroll
    for (int n0 = 0; n0 < 4; ++n0) {
      f32x4 a = {0.f, 0.f, 0.f, 0.f};
#pragma unroll
      for (int ks = 0; ks < 2; ++ks) {
        const float* __restrict__ p = Wk + (size_t)(n0 * 16 + rw) * DD + ks * 32 + kg * 8;
        const short8 bf = pack8(*(const float4*)(p), *(const float4*)(p + 4));
        a = __builtin_amdgcn_mfma_f32_16x16x32_bf16(aq[ks], bf, a, 0, 0, 0);
      }
#pragma unroll
      for (int r = 0; r < 4; ++r) {
        M1T[(size_t)(n0 * 16 + rw) * DD + wid * 16 + kg * 4 + r] = f2bf(a[r]);
      }
    }
    if (wid == 0) {
      const float* __restrict__ wrow = Wk + (size_t)lane * DD;
      float a0 = 0.f, a1 = 0.f, a2 = 0.f, a3 = 0.f;
#pragma unroll
      for (int t2 = 0; t2 < DD; t2 += 4) {
        const float4 w4 = *(const float4*)(wrow + t2);
        a0 = fmaf(w4.x, bq[t2 + 0], a0);
        a1 = fmaf(w4.y, bq[t2 + 1], a1);
        a2 = fmaf(w4.z, bq[t2 + 2], a2);
        a3 = fmaf(w4.w, bq[t2 + 3], a3);
      }
      BKQ[lane] = (a0 + a1) + (a2 + a3);
    }
  } else {
    short8 ao[2];
#pragma unroll
    for (int ks = 0; ks < 2; ++ks) {
      U4S8 t4;
#pragma unroll
      for (int j = 0; j < 4; ++j) {
        const int k = ks * 32 + kg * 8 + 2 * j;
        const int col = wid * 16 + rw;
        ((unsigned int*)&t4)[j] = pk2bf(Wo[(size_t)k * DD + col],
                                        Wo[(size_t)(k + 1) * DD + col]);
      }
      ao[ks] = t4.s8;
    }
#pragma unroll
    for (int n0 = 0; n0 < 4; ++n0) {
      f32x4 a = {0.f, 0.f, 0.f, 0.f};
#pragma unroll
      for (int ks = 0; ks < 2; ++ks) {
        const float* __restrict__ p = Wv + (size_t)(n0 * 16 + rw) * DD + ks * 32 + kg * 8;
        const short8 bf = pack8(*(const float4*)(p), *(const float4*)(p + 4));
        a = __builtin_amdgcn_mfma_f32_16x16x32_bf16(ao[ks], bf, a, 0, 0, 0);
      }
#pragma unroll
      for (int r = 0; r < 4; ++r) {
        WVOT[(size_t)(wid * 16 + kg * 4 + r) * DD + n0 * 16 + rw] = f2bf(a[r]);
      }
    }
    if (wid == 0) {
      float acc = bo[lane];
#pragma unroll 8
      for (int t2 = 0; t2 < DD; ++t2) acc = fmaf(bv[t2], Wo[(size_t)t2 * DD + lane], acc);
      BVO[lane] = acc;
    }
  }
}

// ---------------- main: BYTE-IDENTICAL to round 19 (best passing: 32.2 us) ----------------
__global__ __launch_bounds__(256, 3) void vc_main(
    const int* __restrict__ nodes, const int* __restrict__ hvc,
    const int* __restrict__ hr, const float* __restrict__ v2e,
    const char* __restrict__ ws, float* __restrict__ out, int N) {
  const unsigned short* __restrict__ H = (const unsigned short*)(ws + OFF_H);
  const unsigned short* __restrict__ M1T = (const unsigned short*)(ws + OFF_M1T);
  const unsigned short* __restrict__ WVOT = (const unsigned short*)(ws + OFF_WVOT);
  const float* __restrict__ BKQ = (const float*)(ws + OFF_BKQ);
  const float* __restrict__ BVO = (const float*)(ws + OFF_BVO);

  __shared__ __align__(16) char smem[8 * 6400 + 8 * 68 * 4];
  char* HlB = smem;
  float* sS = (float*)(smem + 8 * 6400);

  const int tid = threadIdx.x;
  const int wid = tid >> 6;    // 0..3; d-quarter n0 == wid
  const int lane = tid & 63;
  const int kg = lane >> 4;
  const int rw = lane & 15;
  const int nb = blockIdx.x * 8;
  const int nA = min(nb + wid, N - 1);
  const int nB = min(nb + 4 + wid, N - 1);

  const int lidx = (lane < LL) ? lane : 0;
  const int idxA = hvc[(size_t)nA * LL + lidx] * NRAT + hr[(size_t)nA * LL + lidx];
  const int idxB = hvc[(size_t)nB * LL + lidx] * NRAT + hr[(size_t)nB * LL + lidx];

  // ---- stage BOTH nodes' H tiles (14 x global_load_lds) ----
  {
    const int chunk = lane & 7;
#pragma unroll
    for (int ph = 0; ph < 2; ++ph) {
      const int idx = ph ? idxB : idxA;
      char* wbase = HlB + (ph ? (4 + wid) : wid) * 6400;
#pragma unroll
      for (int i = 0; i < 7; ++i) {
        const int s = (i < 6) ? (i * 8 + (lane >> 3)) : (42 + (lane >> 3));
        const int sidx = __shfl(idx, s, 64);
        const char* src = (const char*)H + (size_t)sidx * 128 + ((chunk ^ (s & 7)) << 4);
        __builtin_amdgcn_global_load_lds(
            (const __attribute__((address_space(1))) void*)src,
            (__attribute__((address_space(3))) void*)(wbase + ((i < 6) ? i * 1024 : 5376)),
            16, 0, 0);
      }
    }
  }

  // ---- G = X @ M1 + bkq for ALL 8 nodes ----
  {
    const int node_id = nodes[min(nb + (rw & 7), N - 1)];
    const float* __restrict__ xrow = v2e + (size_t)node_id * DD;
    short8 xa[2];
#pragma unroll
    for (int ks = 0; ks < 2; ++ks) {
      xa[ks] = pack8(*(const float4*)(xrow + ks * 32 + kg * 8),
                     *(const float4*)(xrow + ks * 32 + kg * 8 + 4));
    }
    const int n0 = wid;
    f32x4 a = {0.f, 0.f, 0.f, 0.f};
#pragma unroll
    for (int ks = 0; ks < 2; ++ks) {
      const short8 bf = *(const short8*)(M1T + (n0 * 16 + rw) * DD + ks * 32 + kg * 8);
      a = __builtin_amdgcn_mfma_f32_16x16x32_bf16(xa[ks], bf, a, 0, 0, 0);
    }
    if (kg < 2) {   // C rows 0..7 = nodes 0..7
      const float bkqv = BKQ[n0 * 16 + rw];
#pragma unroll
      for (int r = 0; r < 4; ++r) sS[(kg * 4 + r) * 68 + n0 * 16 + rw] = a[r] + bkqv;
    }
  }
  __syncthreads();
  asm volatile("s_waitcnt vmcnt(7)" ::: "memory");  // node A staged; B in flight
  __builtin_amdgcn_sched_barrier(0);

  // ---- ctx base offsets: addr(l) = (l>>3)*1024 + baseo[l&7] (precomputed) ----
  const int sub = (lane & 7) * 2;
  const int hi3 = lane >> 3;
  int baseo[8];
#pragma unroll
  for (int j = 0; j < 8; ++j) baseo[j] = j * 128 + (((hi3 ^ j) << 4) | sub);

  // ---- two per-node phases: A (row wid), then B (row 4+wid) ----
#pragma unroll
  for (int ph = 0; ph < 2; ++ph) {
    const int myrow = ph ? (4 + wid) : wid;
    if (ph == 1) {
      asm volatile("s_waitcnt vmcnt(0)" ::: "memory");  // node B staged
      __builtin_amdgcn_sched_barrier(0);
    }
    const unsigned short* __restrict__ wH =
        (const unsigned short*)(HlB + myrow * 6400);

    short8 ga[2];
#pragma unroll
    for (int ks = 0; ks < 2; ++ks) {
      const float* __restrict__ gp = sS + myrow * 68 + ks * 32 + kg * 8;
      ga[ks] = pack8(*(const float4*)(gp), *(const float4*)(gp + 4));
    }
    float s0, s1, s2, s3;
    {
      f32x4 a;
#pragma unroll
      for (int lt = 0; lt < 4; ++lt) {
        const int s = lt * 16 + rw;
        a = (f32x4){0.f, 0.f, 0.f, 0.f};
#pragma unroll
        for (int ks = 0; ks < 2; ++ks) {
          const int c = (ks * 4 + kg) ^ (s & 7);
          U4S8 hb;
          hb.u4 = *(const uint4*)(wH + s * 64 + c * 8);
          a = __builtin_amdgcn_mfma_f32_16x16x32_bf16(ga[ks], hb.s8, a, 0, 0, 0);
        }
        if (lt == 0) s0 = a[0];
        else if (lt == 1) s1 = a[0];
        else if (lt == 2) s2 = a[0];
        else s3 = a[0];
      }
    }
    s0 *= 0.125f; s1 *= 0.125f; s2 *= 0.125f;
    s3 = (rw < 2) ? s3 * 0.125f : -INFINITY;

    float m = fmaxf(fmaxf(s0, s1), fmaxf(s2, s3));
#pragma unroll
    for (int x = 1; x <= 8; x <<= 1) m = fmaxf(m, __shfl_xor(m, x, 64));
    float e0 = __expf(s0 - m), e1 = __expf(s1 - m), e2 = __expf(s2 - m);
    float e3 = (rw < 2) ? __expf(s3 - m) : 0.f;
    float Z = ((e0 + e1) + (e2 + e3));
#pragma unroll
    for (int x = 1; x <= 8; x <<= 1) Z += __shfl_xor(Z, x, 64);
    const float invZ = 1.f / Z;

    {
      const char* __restrict__ wHb = (const char*)wH;
      float c0 = 0.f, c1 = 0.f;
#define CTX_BLOCK(EREG, BASE, CNT, CACC)                                        \
      _Pragma("unroll")                                                         \
      for (int j = 0; j < (CNT); ++j) {                                         \
        const int l = (BASE) + j;                                               \
        const unsigned short hbb = *(const unsigned short*)(                    \
            wHb + baseo[l & 7] + (l >> 3) * 1024);                              \
        CACC = fmaf(__uint_as_float(((unsigned int)hbb) << 16),                 \
                    rlanef(EREG, j), CACC);                                     \
      }
      CTX_BLOCK(e0, 0, 16, c0)
      CTX_BLOCK(e1, 16, 16, c1)
      CTX_BLOCK(e2, 32, 16, c0)
      CTX_BLOCK(e3, 48, 2, c1)
#undef CTX_BLOCK
      sS[myrow * 68 + lane] = (c0 + c1) * invZ;   // overwrite own row
    }
  }
  __syncthreads();

  // ---- OUT = CTX @ Wvo + bvo for all 8 nodes ----
  {
    short8 ca[2];
#pragma unroll
    for (int ks = 0; ks < 2; ++ks) {
      const float* __restrict__ cp = sS + (rw & 7) * 68 + ks * 32 + kg * 8;
      ca[ks] = pack8(*(const float4*)(cp), *(const float4*)(cp + 4));
    }
    const int n0 = wid;
    f32x4 a = {0.f, 0.f, 0.f, 0.f};
#pragma unroll
    for (int ks = 0; ks < 2; ++ks) {
      const short8 bf = *(const short8*)(WVOT + (n0 * 16 + rw) * DD + ks * 32 + kg * 8);
      a = __builtin_amdgcn_mfma_f32_16x16x32_bf16(ca[ks], bf, a, 0, 0, 0);
    }
    if (kg < 2) {   // C rows 0..7 = nodes 0..7
      const float bvov = BVO[n0 * 16 + rw];
#pragma unroll
      for (int r = 0; r < 4; ++r) {
        const int node = nb + kg * 4 + r;
        if (node < N) out[(size_t)node * DD + n0 * 16 + rw] = a[r] + bvov;
      }
    }
  }
}

extern "C" void kernel_launch(void* const* d_in, const int* in_sizes, int n_in,
                              void* d_out, int out_size, void* d_ws, size_t ws_size,
                              hipStream_t stream) {
  const int* nodes = (const int*)d_in[0];
  const int* hvc = (const int*)d_in[1];
  const int* hr = (const int*)d_in[2];
  const float* c2e = (const float*)d_in[3];
  const float* v2e = (const float*)d_in[4];
  const float* r2e = (const float*)d_in[5];
  const float* W1 = (const float*)d_in[6];
  const float* b1 = (const float*)d_in[7];
  const float* Wq = (const float*)d_in[8];
  const float* bq = (const float*)d_in[9];
  const float* Wk = (const float*)d_in[10];
  const float* bk = (const float*)d_in[11];  // unused: q·bk cancels in softmax
  const float* Wv = (const float*)d_in[12];
  const float* bv = (const float*)d_in[13];
  const float* Wo = (const float*)d_in[14];
  const float* bo = (const float*)d_in[15];
  (void)bk;
  float* out = (float*)d_out;
  char* ws = (char*)d_ws;

  const int N = in_sizes[0];

  prep_v3<<<252, 256, 0, stream>>>(c2e, r2e, W1, b1, Wq, bq, Wk, Wv, Wo, bv, bo, ws);
  vc_main<<<(N + 7) / 8, 256, 0, stream>>>(nodes, hvc, hr, v2e, ws, out, N);
}